// Round 20
// baseline (77.540 us; speedup 1.0000x reference)
//
#include <hip/hip_runtime.h>
#include <hip/hip_bf16.h>

// CapsNet dynamic routing — v14: packed bf16 u_hat layout (halve VMEM ops).
// x: [B=32, N=4096, Din=8], W: [N=4096, C=10, Din=8, D=16], out: [B,C,D] f32.
// Algebra (b0=0): iter0 w=1/C; iter1 logits=u_hat.v0; iter2 logits=u_hat.(v0+v1).
// r19 evidence: bf16 u_hat gained only -4us (sub-byte-proportional) -> A/B are
// VMEM-transaction-bound. Fix: row layout [64x{r0,r1} ushort2 | 32x r2 ushort]
// (same 320B) -> A: 3 stores -> 1 dword + 1 predicated short; B: same for loads.
// r0/r1 are same-lane pairs: no shuffles. r2 valid only lanes<32 (c=8,9).

#define BB 32
#define NN 4096
#define CC 10
#define DIN 8
#define DD 16
#define TPB 512
#define SOUT (BB * CC * DD)           // 5120
#define UHATE ((size_t)BB * NN * CC * DD)   // 20,971,520 bf16 elements (42MB)

#define NCHUNK_A 8
#define GA (NN / NCHUNK_A)            // 512
#define NCHUNK_B 8
#define GB (NN / NCHUNK_B)            // 512

// ---- DPP row-of-16 sum (d-reduce), all lanes get the total ----
template<int CTRL>
__device__ __forceinline__ float dpp_mov(float x) {
    return __int_as_float(__builtin_amdgcn_update_dpp(
        0, __float_as_int(x), CTRL, 0xF, 0xF, true));
}
__device__ __forceinline__ float row_sum16(float x) {
    x += dpp_mov<0xB1>(x);    // quad_perm d^1
    x += dpp_mov<0x4E>(x);    // quad_perm d^2
    x += dpp_mov<0x124>(x);   // row_ror:4
    x += dpp_mov<0x128>(x);   // row_ror:8
    return x;
}

__device__ __forceinline__ unsigned short f2bf(float x) {
    __hip_bfloat16 h = __float2bfloat16(x);
    return *reinterpret_cast<unsigned short*>(&h);
}
__device__ __forceinline__ float bflo(unsigned int p) {
    return __uint_as_float(p << 16);
}
__device__ __forceinline__ float bfhi(unsigned int p) {
    return __uint_as_float(p & 0xffff0000u);
}

// ========== Kernel A: packed u_hat + uniform pass0, LDS-staged ==========
// 8 waves; wave bq handles b=bq*4..bq*4+3. Lane: cq=lane>>4, d=lane&15; c=cq+4r.
// u_hat row (b,n): uint[80]: [0..63]={r0,r1} per lane; shorts[128..159]=r2 lanes<32.
__global__ __launch_bounds__(TPB) void caps_uhat_pass0(
    const float* __restrict__ xg,
    const float* __restrict__ Wg,
    unsigned int* __restrict__ uhat,   // [B*N][80] uints
    float* __restrict__ part)          // [GA][SOUT]
{
    __shared__ float Wl[NCHUNK_A * CC * DIN * DD];  // 40KB, swizzled [j][R][i]

    const int t    = threadIdx.x;
    const int lane = t & 63;
    const int bqu  = __builtin_amdgcn_readfirstlane(t >> 6);
    const int cq   = lane >> 4;
    const int d    = lane & 15;
    const int n0   = blockIdx.x * NCHUNK_A;

    float acc[4][3];
    #pragma unroll
    for (int bb = 0; bb < 4; ++bb)
        #pragma unroll
        for (int r = 0; r < 3; ++r) acc[bb][r] = 0.f;

    // stage W for 8 planes (2560 float4), transposed + swizzled
    {
        const float4* WgV = (const float4*)Wg;
        #pragma unroll
        for (int wi = 0; wi < 5; ++wi) {
            int m4 = t + wi * TPB;              // 0..2559
            int j  = m4 / 320;
            int q  = m4 - j * 320;
            int c  = q >> 5, i = (q & 31) >> 2, d0 = (q & 3) << 2;
            float4 v = WgV[(size_t)n0 * 320 + m4];
            const float* vf = (const float*)&v;
            float* plane = Wl + j * 1280;
            int h = i >> 2, wd = i & 3;
            #pragma unroll
            for (int k = 0; k < 4; ++k) {
                int R = c * DD + d0 + k;
                int U = (R * 2 + h) ^ ((R >> 2) & 7);
                plane[U * 4 + wd] = vf[k];
            }
        }
    }
    __syncthreads();

    #pragma unroll 1   // prevent unroll -> register blowup (r11)
    for (int j = 0; j < NCHUNK_A; ++j) {
        const float4* planeV = (const float4*)(Wl + j * 1280);
        const int n = n0 + j;

        // u rows: wave-uniform -> scalar loads
        float ub[4][8];
        #pragma unroll
        for (int bb = 0; bb < 4; ++bb) {
            const float* up = xg + ((size_t)(bqu * 4 + bb) * NN + n) * DIN;
            #pragma unroll
            for (int i = 0; i < 8; ++i) ub[bb][i] = up[i];
        }

        // W fragments for the 3 r-slices (one at a time), uh per bb
        float uh[4][3];
        #pragma unroll
        for (int r = 0; r < 3; ++r) {
            const int c = cq + 4 * r;
            float w0=0,w1=0,w2=0,w3=0,w4=0,w5=0,w6=0,w7=0;
            if (c < CC) {
                int R  = c * DD + d;
                int sw = (R >> 2) & 7;
                float4 a0 = planeV[(R * 2) ^ sw];
                float4 a1 = planeV[(R * 2 + 1) ^ sw];
                w0=a0.x; w1=a0.y; w2=a0.z; w3=a0.w;
                w4=a1.x; w5=a1.y; w6=a1.z; w7=a1.w;
            }
            #pragma unroll
            for (int bb = 0; bb < 4; ++bb) {
                float s = 0.f;
                s = fmaf(ub[bb][0], w0, s); s = fmaf(ub[bb][1], w1, s);
                s = fmaf(ub[bb][2], w2, s); s = fmaf(ub[bb][3], w3, s);
                s = fmaf(ub[bb][4], w4, s); s = fmaf(ub[bb][5], w5, s);
                s = fmaf(ub[bb][6], w6, s); s = fmaf(ub[bb][7], w7, s);
                uh[bb][r] = s;
                acc[bb][r] += s;
            }
        }

        // packed stores: 1 dword (r0,r1) + 1 predicated short (r2, lanes<32)
        #pragma unroll
        for (int bb = 0; bb < 4; ++bb) {
            const int b = bqu * 4 + bb;
            unsigned int* rowU = uhat + (size_t)(b * NN + n) * 80;
            unsigned int p = (unsigned int)f2bf(uh[bb][0])
                           | ((unsigned int)f2bf(uh[bb][1]) << 16);
            rowU[lane] = p;
            if (lane < 32) {
                unsigned short* rowS = (unsigned short*)rowU;
                rowS[128 + lane] = f2bf(uh[bb][2]);
            }
        }
    }

    float* dst = part + (size_t)blockIdx.x * SOUT;
    #pragma unroll
    for (int bb = 0; bb < 4; ++bb) {
        int b = bqu * 4 + bb;
        #pragma unroll
        for (int r = 0; r < 3; ++r) {
            int c = cq + 4 * r;
            if (c < CC) dst[(b * CC + c) * DD + d] = acc[bb][r] * (1.0f / CC);
        }
    }
}

// ========== Kernel B: routed pass streaming packed u_hat ==========
__global__ __launch_bounds__(TPB) void caps_routed(
    const unsigned int* __restrict__ uhat,  // [B*N][80] uints
    const float* __restrict__ vprev,        // [B,C,D]
    float* __restrict__ part)               // [GB][SOUT]
{
    const int t    = threadIdx.x;
    const int lane = t & 63;
    const int bqu  = __builtin_amdgcn_readfirstlane(t >> 6);
    const int cq   = lane >> 4;
    const int d    = lane & 15;

    float vv[4][3];
    #pragma unroll
    for (int bb = 0; bb < 4; ++bb) {
        int b = bqu * 4 + bb;
        #pragma unroll
        for (int r = 0; r < 3; ++r) {
            int c = cq + 4 * r;
            vv[bb][r] = (c < CC) ? vprev[(b * CC + c) * DD + d] : 0.f;
        }
    }

    float acc[4][3];
    #pragma unroll
    for (int bb = 0; bb < 4; ++bb)
        #pragma unroll
        for (int r = 0; r < 3; ++r) acc[bb][r] = 0.f;

    const int n0 = blockIdx.x * NCHUNK_B;

    #pragma unroll 1
    for (int j = 0; j < NCHUNK_B; ++j) {
        const int n = n0 + j;
        float uh[4][3];
        #pragma unroll
        for (int bb = 0; bb < 4; ++bb) {
            const unsigned int* rowU =
                uhat + (size_t)((bqu * 4 + bb) * NN + n) * 80;
            unsigned int p = rowU[lane];                 // r0,r1 packed
            uh[bb][0] = bflo(p);
            uh[bb][1] = bfhi(p);
            float u2 = 0.f;
            if (lane < 32) {
                const unsigned short* rowS = (const unsigned short*)rowU;
                u2 = __uint_as_float((unsigned int)rowS[128 + lane] << 16);
            }
            uh[bb][2] = u2;
        }
        #pragma unroll
        for (int bb = 0; bb < 4; ++bb) {
            float dot0 = row_sum16(uh[bb][0] * vv[bb][0]);
            float dot1 = row_sum16(uh[bb][1] * vv[bb][1]);
            float dot2 = row_sum16(uh[bb][2] * vv[bb][2]);
            // no max-subtract: |dot| bounded (~2), exp safe (r12-verified)
            float e0 = __expf(dot0);
            float e1 = __expf(dot1);
            float e2 = (cq < 2) ? __expf(dot2) : 0.f;
            float den = e0 + e1 + e2;
            den += __shfl_xor(den, 16, 64);
            den += __shfl_xor(den, 32, 64);
            float inv = __builtin_amdgcn_rcpf(den);
            acc[bb][0] = fmaf(e0 * inv, uh[bb][0], acc[bb][0]);
            acc[bb][1] = fmaf(e1 * inv, uh[bb][1], acc[bb][1]);
            acc[bb][2] = fmaf(e2 * inv, uh[bb][2], acc[bb][2]);
        }
    }

    float* dst = part + (size_t)blockIdx.x * SOUT;
    #pragma unroll
    for (int bb = 0; bb < 4; ++bb) {
        int b = bqu * 4 + bb;
        #pragma unroll
        for (int r = 0; r < 3; ++r) {
            int c = cq + 4 * r;
            if (c < CC) dst[(b * CC + c) * DD + d] = acc[bb][r];
        }
    }
}

// ===== Fused cross-block reduce + squash, TPB=1024, any G (stride-64) =====
// MODE 0: vsum=v ; 1: vsum+=v ; 2: outF=v
template<int MODE>
__global__ __launch_bounds__(1024) void caps_reduce(
    const float* __restrict__ part,   // [G][SOUT]
    int G,
    float* __restrict__ vsum,
    float* __restrict__ outF)
{
    __shared__ float red[1024];
    const int row = blockIdx.x;       // b*CC + c
    const int t = threadIdx.x;
    const int d = t & 15, ks = t >> 4;             // 64 k-slices
    const float* p = part + row * DD + d;
    float s = 0.f;
    for (int s_i = ks; s_i < G; s_i += 64)
        s += p[(size_t)s_i * SOUT];
    red[t] = s;
    __syncthreads();
    if (t < 16) {
        float sd = 0.f;
        #pragma unroll
        for (int k2 = 0; k2 < 64; ++k2) sd += red[k2 * 16 + t];
        float s2 = sd * sd;
        #pragma unroll
        for (int m = 1; m < 16; m <<= 1) s2 += __shfl_xor(s2, m, 64);
        float f = s2 / ((1.f + s2) * sqrtf(s2 + 1e-7f));
        float v = f * sd;
        int idx = row * DD + t;
        if (MODE == 0) vsum[idx] = v;
        if (MODE == 1) vsum[idx] += v;
        if (MODE == 2) outF[idx] = v;
    }
}

// ======== Fallback (r14-proven): LDS recompute pass, grid-stride ========
template<int UNIFORM, int PARTIALS>
__global__ __launch_bounds__(TPB) void caps_pass(
    const float* __restrict__ xg,
    const float* __restrict__ Wg,
    const float* __restrict__ vprev,
    float* __restrict__ outp)
{
    __shared__ float Wl[NCHUNK_B * CC * DIN * DD];

    const int t    = threadIdx.x;
    const int lane = t & 63;
    const int bqu  = __builtin_amdgcn_readfirstlane(t >> 6);
    const int cq   = lane >> 4;
    const int d    = lane & 15;

    float vv[4][3];
    if (!UNIFORM) {
        #pragma unroll
        for (int bb = 0; bb < 4; ++bb) {
            int b = bqu * 4 + bb;
            #pragma unroll
            for (int r = 0; r < 3; ++r) {
                int c = cq + 4 * r;
                vv[bb][r] = (c < CC) ? vprev[(b * CC + c) * DD + d] : 0.f;
            }
        }
    }

    float acc[4][3];
    #pragma unroll
    for (int bb = 0; bb < 4; ++bb)
        #pragma unroll
        for (int r = 0; r < 3; ++r) acc[bb][r] = 0.f;

    for (int chunk = blockIdx.x; chunk < GB; chunk += gridDim.x) {
        const int n0 = chunk * NCHUNK_B;
        {
            const float4* WgV = (const float4*)Wg;
            #pragma unroll
            for (int wi = 0; wi < 5; ++wi) {
                int m4 = t + wi * TPB;
                int j = m4 / 320, q = m4 - j * 320;
                int c = q >> 5, i = (q & 31) >> 2, d0 = (q & 3) << 2;
                float4 v = WgV[(size_t)n0 * 320 + m4];
                const float* vf = (const float*)&v;
                float* plane = Wl + j * 1280;
                int h = i >> 2, wd = i & 3;
                #pragma unroll
                for (int k = 0; k < 4; ++k) {
                    int R = c * DD + d0 + k;
                    int U = (R * 2 + h) ^ ((R >> 2) & 7);
                    plane[U * 4 + wd] = vf[k];
                }
            }
        }
        __syncthreads();

        #pragma unroll 1
        for (int j = 0; j < NCHUNK_B; ++j) {
            const float4* planeV = (const float4*)(Wl + j * 1280);
            float ub[4][8];
            #pragma unroll
            for (int bb = 0; bb < 4; ++bb) {
                const float* up = xg + ((size_t)(bqu * 4 + bb) * NN + n0 + j) * DIN;
                #pragma unroll
                for (int i = 0; i < 8; ++i) ub[bb][i] = up[i];
            }
            float uh[4][3];
            #pragma unroll
            for (int r = 0; r < 3; ++r) {
                int c = cq + 4 * r;
                float w0=0,w1=0,w2=0,w3=0,w4=0,w5=0,w6=0,w7=0;
                if (c < CC) {
                    int R = c * DD + d, sw = (R >> 2) & 7;
                    float4 a0 = planeV[(R * 2) ^ sw];
                    float4 a1 = planeV[(R * 2 + 1) ^ sw];
                    w0=a0.x; w1=a0.y; w2=a0.z; w3=a0.w;
                    w4=a1.x; w5=a1.y; w6=a1.z; w7=a1.w;
                }
                #pragma unroll
                for (int bb = 0; bb < 4; ++bb) {
                    float s = 0.f;
                    s = fmaf(ub[bb][0], w0, s); s = fmaf(ub[bb][1], w1, s);
                    s = fmaf(ub[bb][2], w2, s); s = fmaf(ub[bb][3], w3, s);
                    s = fmaf(ub[bb][4], w4, s); s = fmaf(ub[bb][5], w5, s);
                    s = fmaf(ub[bb][6], w6, s); s = fmaf(ub[bb][7], w7, s);
                    uh[bb][r] = s;
                }
            }
            #pragma unroll
            for (int bb = 0; bb < 4; ++bb) {
                float w0, w1, w2;
                if (UNIFORM) { w0 = w1 = w2 = 1.0f / CC; }
                else {
                    float dot0 = row_sum16(uh[bb][0] * vv[bb][0]);
                    float dot1 = row_sum16(uh[bb][1] * vv[bb][1]);
                    float dot2 = row_sum16(uh[bb][2] * vv[bb][2]);
                    float e0 = __expf(dot0), e1 = __expf(dot1);
                    float e2 = (cq < 2) ? __expf(dot2) : 0.f;
                    float den = e0 + e1 + e2;
                    den += __shfl_xor(den, 16, 64);
                    den += __shfl_xor(den, 32, 64);
                    float inv = __builtin_amdgcn_rcpf(den);
                    w0 = e0 * inv; w1 = e1 * inv; w2 = e2 * inv;
                }
                acc[bb][0] = fmaf(w0, uh[bb][0], acc[bb][0]);
                acc[bb][1] = fmaf(w1, uh[bb][1], acc[bb][1]);
                acc[bb][2] = fmaf(w2, uh[bb][2], acc[bb][2]);
            }
        }
        __syncthreads();
    }

    #pragma unroll
    for (int bb = 0; bb < 4; ++bb) {
        int b = bqu * 4 + bb;
        #pragma unroll
        for (int r = 0; r < 3; ++r) {
            int c = cq + 4 * r;
            if (c < CC) {
                if (PARTIALS) (outp + (size_t)blockIdx.x * SOUT)[(b * CC + c) * DD + d] = acc[bb][r];
                else atomicAdd(&outp[(b * CC + c) * DD + d], acc[bb][r]);
            }
        }
    }
}

// Atomic-fallback squash.
template<int MODE>
__global__ __launch_bounds__(512) void caps_squash(
    const float* __restrict__ sIn, float* __restrict__ vsum,
    float* __restrict__ outF)
{
    int r = blockIdx.x * blockDim.x + threadIdx.x;
    if (r >= BB * CC) return;
    const float* p = sIn + (size_t)r * DD;
    float sv[DD]; float s2 = 0.f;
    #pragma unroll
    for (int d = 0; d < DD; ++d) { sv[d] = p[d]; s2 = fmaf(sv[d], sv[d], s2); }
    float f = s2 / ((1.f + s2) * sqrtf(s2 + 1e-7f));
    #pragma unroll
    for (int d = 0; d < DD; ++d) {
        float v = f * sv[d];
        int idx = r * DD + d;
        if (MODE == 0) vsum[idx] = v;
        if (MODE == 1) vsum[idx] += v;
        if (MODE == 2) outF[idx] = v;
    }
}

extern "C" void kernel_launch(void* const* d_in, const int* in_sizes, int n_in,
                              void* d_out, int out_size, void* d_ws, size_t ws_size,
                              hipStream_t stream) {
    const float* x; const float* Wt;
    if (in_sizes[0] == BB * NN * DIN) { x = (const float*)d_in[0]; Wt = (const float*)d_in[1]; }
    else                              { Wt = (const float*)d_in[0]; x = (const float*)d_in[1]; }
    float* out = (float*)d_out;
    float* ws = (float*)d_ws;

    const size_t uhat_floats = UHATE / 2;   // bf16 elems in float-slot units
    const size_t need = UHATE * 2 + (size_t)(GA + 1) * SOUT * sizeof(float);

    if (ws_size >= need) {
        unsigned int* uhat = (unsigned int*)ws;
        float* part = ws + uhat_floats;        // [GA][SOUT]
        float* vsum = part + (size_t)GA * SOUT;
        caps_uhat_pass0<<<GA, TPB, 0, stream>>>(x, Wt, uhat, part);
        caps_reduce<0><<<BB*CC, 1024, 0, stream>>>(part, GA, vsum, nullptr);
        caps_routed<<<GB, TPB, 0, stream>>>(uhat, vsum, part);
        caps_reduce<1><<<BB*CC, 1024, 0, stream>>>(part, GB, vsum, nullptr);
        caps_routed<<<GB, TPB, 0, stream>>>(uhat, vsum, part);
        caps_reduce<2><<<BB*CC, 1024, 0, stream>>>(part, GB, vsum, out);
    } else {
        // r14-proven fallback
        const size_t wsf = ws_size / sizeof(float);
        int Gf = 0;
        const int cands[5] = {512, 256, 128, 64, 32};
        for (int ci = 0; ci < 5; ++ci)
            if (wsf >= (size_t)(cands[ci] + 1) * SOUT) { Gf = cands[ci]; break; }
        if (Gf > 0) {
            float* part = ws;
            float* vsum = ws + (size_t)Gf * SOUT;
            caps_pass<1,1><<<Gf, TPB, 0, stream>>>(x, Wt, nullptr, part);
            caps_reduce<0><<<BB*CC, 1024, 0, stream>>>(part, Gf, vsum, nullptr);
            caps_pass<0,1><<<Gf, TPB, 0, stream>>>(x, Wt, vsum, part);
            caps_reduce<1><<<BB*CC, 1024, 0, stream>>>(part, Gf, vsum, nullptr);
            caps_pass<0,1><<<Gf, TPB, 0, stream>>>(x, Wt, vsum, part);
            caps_reduce<2><<<BB*CC, 1024, 0, stream>>>(part, Gf, vsum, out);
        } else {
            float* sAcc = ws;
            float* vsum = ws + SOUT;
            hipMemsetAsync(sAcc, 0, SOUT * sizeof(float), stream);
            caps_pass<1,0><<<64, TPB, 0, stream>>>(x, Wt, nullptr, sAcc);
            caps_squash<0><<<1, 512, 0, stream>>>(sAcc, vsum, nullptr);
            hipMemsetAsync(sAcc, 0, SOUT * sizeof(float), stream);
            caps_pass<0,0><<<64, TPB, 0, stream>>>(x, Wt, vsum, sAcc);
            caps_squash<1><<<1, 512, 0, stream>>>(sAcc, vsum, nullptr);
            hipMemsetAsync(sAcc, 0, SOUT * sizeof(float), stream);
            caps_pass<0,0><<<64, TPB, 0, stream>>>(x, Wt, vsum, sAcc);
            caps_squash<2><<<1, 512, 0, stream>>>(sAcc, nullptr, out);
        }
    }
}

// Round 21
// 75.428 us; speedup vs baseline: 1.0280x; 1.0280x over previous
//
#include <hip/hip_runtime.h>
#include <hip/hip_bf16.h>

// CapsNet dynamic routing — v15: v14 + unroll-2 j-loops (double MLP).
// x: [B=32, N=4096, Din=8], W: [N=4096, C=10, Din=8, D=16], out: [B,C,D] f32.
// Algebra (b0=0): iter0 w=1/C; iter1 logits=u_hat.v0; iter2 logits=u_hat.(v0+v1).
// r20 evidence: bytes (v13 small win) and transactions (v14 nil) exhausted;
// A/B j-loops at unroll-1 keep ONE load-chain in flight per thread. VGPR is
// 28-30 (cap 128) -> unroll 2 is spill-safe and doubles outstanding loads.

#define BB 32
#define NN 4096
#define CC 10
#define DIN 8
#define DD 16
#define TPB 512
#define SOUT (BB * CC * DD)           // 5120
#define UHATE ((size_t)BB * NN * CC * DD)   // 20,971,520 bf16 elements (42MB)

#define NCHUNK_A 8
#define GA (NN / NCHUNK_A)            // 512
#define NCHUNK_B 8
#define GB (NN / NCHUNK_B)            // 512

// ---- DPP row-of-16 sum (d-reduce), all lanes get the total ----
template<int CTRL>
__device__ __forceinline__ float dpp_mov(float x) {
    return __int_as_float(__builtin_amdgcn_update_dpp(
        0, __float_as_int(x), CTRL, 0xF, 0xF, true));
}
__device__ __forceinline__ float row_sum16(float x) {
    x += dpp_mov<0xB1>(x);    // quad_perm d^1
    x += dpp_mov<0x4E>(x);    // quad_perm d^2
    x += dpp_mov<0x124>(x);   // row_ror:4
    x += dpp_mov<0x128>(x);   // row_ror:8
    return x;
}

__device__ __forceinline__ unsigned short f2bf(float x) {
    __hip_bfloat16 h = __float2bfloat16(x);
    return *reinterpret_cast<unsigned short*>(&h);
}
__device__ __forceinline__ float bflo(unsigned int p) {
    return __uint_as_float(p << 16);
}
__device__ __forceinline__ float bfhi(unsigned int p) {
    return __uint_as_float(p & 0xffff0000u);
}

// ========== Kernel A: packed u_hat + uniform pass0, LDS-staged ==========
// 8 waves; wave bq handles b=bq*4..bq*4+3. Lane: cq=lane>>4, d=lane&15; c=cq+4r.
// u_hat row (b,n): uint[80]: [0..63]={r0,r1} per lane; shorts[128..159]=r2 lanes<32.
__global__ __launch_bounds__(TPB) void caps_uhat_pass0(
    const float* __restrict__ xg,
    const float* __restrict__ Wg,
    unsigned int* __restrict__ uhat,   // [B*N][80] uints
    float* __restrict__ part)          // [GA][SOUT]
{
    __shared__ float Wl[NCHUNK_A * CC * DIN * DD];  // 40KB, swizzled [j][R][i]

    const int t    = threadIdx.x;
    const int lane = t & 63;
    const int bqu  = __builtin_amdgcn_readfirstlane(t >> 6);
    const int cq   = lane >> 4;
    const int d    = lane & 15;
    const int n0   = blockIdx.x * NCHUNK_A;

    float acc[4][3];
    #pragma unroll
    for (int bb = 0; bb < 4; ++bb)
        #pragma unroll
        for (int r = 0; r < 3; ++r) acc[bb][r] = 0.f;

    // stage W for 8 planes (2560 float4), transposed + swizzled
    {
        const float4* WgV = (const float4*)Wg;
        #pragma unroll
        for (int wi = 0; wi < 5; ++wi) {
            int m4 = t + wi * TPB;              // 0..2559
            int j  = m4 / 320;
            int q  = m4 - j * 320;
            int c  = q >> 5, i = (q & 31) >> 2, d0 = (q & 3) << 2;
            float4 v = WgV[(size_t)n0 * 320 + m4];
            const float* vf = (const float*)&v;
            float* plane = Wl + j * 1280;
            int h = i >> 2, wd = i & 3;
            #pragma unroll
            for (int k = 0; k < 4; ++k) {
                int R = c * DD + d0 + k;
                int U = (R * 2 + h) ^ ((R >> 2) & 7);
                plane[U * 4 + wd] = vf[k];
            }
        }
    }
    __syncthreads();

    #pragma unroll 2   // 2-deep: doubles load MLP; VGPR 28 -> spill-safe
    for (int j = 0; j < NCHUNK_A; ++j) {
        const float4* planeV = (const float4*)(Wl + j * 1280);
        const int n = n0 + j;

        // u rows: wave-uniform -> scalar loads
        float ub[4][8];
        #pragma unroll
        for (int bb = 0; bb < 4; ++bb) {
            const float* up = xg + ((size_t)(bqu * 4 + bb) * NN + n) * DIN;
            #pragma unroll
            for (int i = 0; i < 8; ++i) ub[bb][i] = up[i];
        }

        // W fragments for the 3 r-slices (one at a time), uh per bb
        float uh[4][3];
        #pragma unroll
        for (int r = 0; r < 3; ++r) {
            const int c = cq + 4 * r;
            float w0=0,w1=0,w2=0,w3=0,w4=0,w5=0,w6=0,w7=0;
            if (c < CC) {
                int R  = c * DD + d;
                int sw = (R >> 2) & 7;
                float4 a0 = planeV[(R * 2) ^ sw];
                float4 a1 = planeV[(R * 2 + 1) ^ sw];
                w0=a0.x; w1=a0.y; w2=a0.z; w3=a0.w;
                w4=a1.x; w5=a1.y; w6=a1.z; w7=a1.w;
            }
            #pragma unroll
            for (int bb = 0; bb < 4; ++bb) {
                float s = 0.f;
                s = fmaf(ub[bb][0], w0, s); s = fmaf(ub[bb][1], w1, s);
                s = fmaf(ub[bb][2], w2, s); s = fmaf(ub[bb][3], w3, s);
                s = fmaf(ub[bb][4], w4, s); s = fmaf(ub[bb][5], w5, s);
                s = fmaf(ub[bb][6], w6, s); s = fmaf(ub[bb][7], w7, s);
                uh[bb][r] = s;
                acc[bb][r] += s;
            }
        }

        // packed stores: 1 dword (r0,r1) + 1 predicated short (r2, lanes<32)
        #pragma unroll
        for (int bb = 0; bb < 4; ++bb) {
            const int b = bqu * 4 + bb;
            unsigned int* rowU = uhat + (size_t)(b * NN + n) * 80;
            unsigned int p = (unsigned int)f2bf(uh[bb][0])
                           | ((unsigned int)f2bf(uh[bb][1]) << 16);
            rowU[lane] = p;
            if (lane < 32) {
                unsigned short* rowS = (unsigned short*)rowU;
                rowS[128 + lane] = f2bf(uh[bb][2]);
            }
        }
    }

    float* dst = part + (size_t)blockIdx.x * SOUT;
    #pragma unroll
    for (int bb = 0; bb < 4; ++bb) {
        int b = bqu * 4 + bb;
        #pragma unroll
        for (int r = 0; r < 3; ++r) {
            int c = cq + 4 * r;
            if (c < CC) dst[(b * CC + c) * DD + d] = acc[bb][r] * (1.0f / CC);
        }
    }
}

// ========== Kernel B: routed pass streaming packed u_hat ==========
__global__ __launch_bounds__(TPB) void caps_routed(
    const unsigned int* __restrict__ uhat,  // [B*N][80] uints
    const float* __restrict__ vprev,        // [B,C,D]
    float* __restrict__ part)               // [GB][SOUT]
{
    const int t    = threadIdx.x;
    const int lane = t & 63;
    const int bqu  = __builtin_amdgcn_readfirstlane(t >> 6);
    const int cq   = lane >> 4;
    const int d    = lane & 15;

    float vv[4][3];
    #pragma unroll
    for (int bb = 0; bb < 4; ++bb) {
        int b = bqu * 4 + bb;
        #pragma unroll
        for (int r = 0; r < 3; ++r) {
            int c = cq + 4 * r;
            vv[bb][r] = (c < CC) ? vprev[(b * CC + c) * DD + d] : 0.f;
        }
    }

    float acc[4][3];
    #pragma unroll
    for (int bb = 0; bb < 4; ++bb)
        #pragma unroll
        for (int r = 0; r < 3; ++r) acc[bb][r] = 0.f;

    const int n0 = blockIdx.x * NCHUNK_B;

    #pragma unroll 2   // 2-deep: doubles load MLP; VGPR ~30 -> spill-safe
    for (int j = 0; j < NCHUNK_B; ++j) {
        const int n = n0 + j;
        float uh[4][3];
        #pragma unroll
        for (int bb = 0; bb < 4; ++bb) {
            const unsigned int* rowU =
                uhat + (size_t)((bqu * 4 + bb) * NN + n) * 80;
            unsigned int p = rowU[lane];                 // r0,r1 packed
            uh[bb][0] = bflo(p);
            uh[bb][1] = bfhi(p);
            float u2 = 0.f;
            if (lane < 32) {
                const unsigned short* rowS = (const unsigned short*)rowU;
                u2 = __uint_as_float((unsigned int)rowS[128 + lane] << 16);
            }
            uh[bb][2] = u2;
        }
        #pragma unroll
        for (int bb = 0; bb < 4; ++bb) {
            float dot0 = row_sum16(uh[bb][0] * vv[bb][0]);
            float dot1 = row_sum16(uh[bb][1] * vv[bb][1]);
            float dot2 = row_sum16(uh[bb][2] * vv[bb][2]);
            // no max-subtract: |dot| bounded (~2), exp safe (r12-verified)
            float e0 = __expf(dot0);
            float e1 = __expf(dot1);
            float e2 = (cq < 2) ? __expf(dot2) : 0.f;
            float den = e0 + e1 + e2;
            den += __shfl_xor(den, 16, 64);
            den += __shfl_xor(den, 32, 64);
            float inv = __builtin_amdgcn_rcpf(den);
            acc[bb][0] = fmaf(e0 * inv, uh[bb][0], acc[bb][0]);
            acc[bb][1] = fmaf(e1 * inv, uh[bb][1], acc[bb][1]);
            acc[bb][2] = fmaf(e2 * inv, uh[bb][2], acc[bb][2]);
        }
    }

    float* dst = part + (size_t)blockIdx.x * SOUT;
    #pragma unroll
    for (int bb = 0; bb < 4; ++bb) {
        int b = bqu * 4 + bb;
        #pragma unroll
        for (int r = 0; r < 3; ++r) {
            int c = cq + 4 * r;
            if (c < CC) dst[(b * CC + c) * DD + d] = acc[bb][r];
        }
    }
}

// ===== Fused cross-block reduce + squash, TPB=1024, any G (stride-64) =====
// MODE 0: vsum=v ; 1: vsum+=v ; 2: outF=v
template<int MODE>
__global__ __launch_bounds__(1024) void caps_reduce(
    const float* __restrict__ part,   // [G][SOUT]
    int G,
    float* __restrict__ vsum,
    float* __restrict__ outF)
{
    __shared__ float red[1024];
    const int row = blockIdx.x;       // b*CC + c
    const int t = threadIdx.x;
    const int d = t & 15, ks = t >> 4;             // 64 k-slices
    const float* p = part + row * DD + d;
    float s = 0.f;
    for (int s_i = ks; s_i < G; s_i += 64)
        s += p[(size_t)s_i * SOUT];
    red[t] = s;
    __syncthreads();
    if (t < 16) {
        float sd = 0.f;
        #pragma unroll
        for (int k2 = 0; k2 < 64; ++k2) sd += red[k2 * 16 + t];
        float s2 = sd * sd;
        #pragma unroll
        for (int m = 1; m < 16; m <<= 1) s2 += __shfl_xor(s2, m, 64);
        float f = s2 / ((1.f + s2) * sqrtf(s2 + 1e-7f));
        float v = f * sd;
        int idx = row * DD + t;
        if (MODE == 0) vsum[idx] = v;
        if (MODE == 1) vsum[idx] += v;
        if (MODE == 2) outF[idx] = v;
    }
}

// ======== Fallback (r14-proven): LDS recompute pass, grid-stride ========
template<int UNIFORM, int PARTIALS>
__global__ __launch_bounds__(TPB) void caps_pass(
    const float* __restrict__ xg,
    const float* __restrict__ Wg,
    const float* __restrict__ vprev,
    float* __restrict__ outp)
{
    __shared__ float Wl[NCHUNK_B * CC * DIN * DD];

    const int t    = threadIdx.x;
    const int lane = t & 63;
    const int bqu  = __builtin_amdgcn_readfirstlane(t >> 6);
    const int cq   = lane >> 4;
    const int d    = lane & 15;

    float vv[4][3];
    if (!UNIFORM) {
        #pragma unroll
        for (int bb = 0; bb < 4; ++bb) {
            int b = bqu * 4 + bb;
            #pragma unroll
            for (int r = 0; r < 3; ++r) {
                int c = cq + 4 * r;
                vv[bb][r] = (c < CC) ? vprev[(b * CC + c) * DD + d] : 0.f;
            }
        }
    }

    float acc[4][3];
    #pragma unroll
    for (int bb = 0; bb < 4; ++bb)
        #pragma unroll
        for (int r = 0; r < 3; ++r) acc[bb][r] = 0.f;

    for (int chunk = blockIdx.x; chunk < GB; chunk += gridDim.x) {
        const int n0 = chunk * NCHUNK_B;
        {
            const float4* WgV = (const float4*)Wg;
            #pragma unroll
            for (int wi = 0; wi < 5; ++wi) {
                int m4 = t + wi * TPB;
                int j = m4 / 320, q = m4 - j * 320;
                int c = q >> 5, i = (q & 31) >> 2, d0 = (q & 3) << 2;
                float4 v = WgV[(size_t)n0 * 320 + m4];
                const float* vf = (const float*)&v;
                float* plane = Wl + j * 1280;
                int h = i >> 2, wd = i & 3;
                #pragma unroll
                for (int k = 0; k < 4; ++k) {
                    int R = c * DD + d0 + k;
                    int U = (R * 2 + h) ^ ((R >> 2) & 7);
                    plane[U * 4 + wd] = vf[k];
                }
            }
        }
        __syncthreads();

        #pragma unroll 1
        for (int j = 0; j < NCHUNK_B; ++j) {
            const float4* planeV = (const float4*)(Wl + j * 1280);
            float ub[4][8];
            #pragma unroll
            for (int bb = 0; bb < 4; ++bb) {
                const float* up = xg + ((size_t)(bqu * 4 + bb) * NN + n0 + j) * DIN;
                #pragma unroll
                for (int i = 0; i < 8; ++i) ub[bb][i] = up[i];
            }
            float uh[4][3];
            #pragma unroll
            for (int r = 0; r < 3; ++r) {
                int c = cq + 4 * r;
                float w0=0,w1=0,w2=0,w3=0,w4=0,w5=0,w6=0,w7=0;
                if (c < CC) {
                    int R = c * DD + d, sw = (R >> 2) & 7;
                    float4 a0 = planeV[(R * 2) ^ sw];
                    float4 a1 = planeV[(R * 2 + 1) ^ sw];
                    w0=a0.x; w1=a0.y; w2=a0.z; w3=a0.w;
                    w4=a1.x; w5=a1.y; w6=a1.z; w7=a1.w;
                }
                #pragma unroll
                for (int bb = 0; bb < 4; ++bb) {
                    float s = 0.f;
                    s = fmaf(ub[bb][0], w0, s); s = fmaf(ub[bb][1], w1, s);
                    s = fmaf(ub[bb][2], w2, s); s = fmaf(ub[bb][3], w3, s);
                    s = fmaf(ub[bb][4], w4, s); s = fmaf(ub[bb][5], w5, s);
                    s = fmaf(ub[bb][6], w6, s); s = fmaf(ub[bb][7], w7, s);
                    uh[bb][r] = s;
                }
            }
            #pragma unroll
            for (int bb = 0; bb < 4; ++bb) {
                float w0, w1, w2;
                if (UNIFORM) { w0 = w1 = w2 = 1.0f / CC; }
                else {
                    float dot0 = row_sum16(uh[bb][0] * vv[bb][0]);
                    float dot1 = row_sum16(uh[bb][1] * vv[bb][1]);
                    float dot2 = row_sum16(uh[bb][2] * vv[bb][2]);
                    float e0 = __expf(dot0), e1 = __expf(dot1);
                    float e2 = (cq < 2) ? __expf(dot2) : 0.f;
                    float den = e0 + e1 + e2;
                    den += __shfl_xor(den, 16, 64);
                    den += __shfl_xor(den, 32, 64);
                    float inv = __builtin_amdgcn_rcpf(den);
                    w0 = e0 * inv; w1 = e1 * inv; w2 = e2 * inv;
                }
                acc[bb][0] = fmaf(w0, uh[bb][0], acc[bb][0]);
                acc[bb][1] = fmaf(w1, uh[bb][1], acc[bb][1]);
                acc[bb][2] = fmaf(w2, uh[bb][2], acc[bb][2]);
            }
        }
        __syncthreads();
    }

    #pragma unroll
    for (int bb = 0; bb < 4; ++bb) {
        int b = bqu * 4 + bb;
        #pragma unroll
        for (int r = 0; r < 3; ++r) {
            int c = cq + 4 * r;
            if (c < CC) {
                if (PARTIALS) (outp + (size_t)blockIdx.x * SOUT)[(b * CC + c) * DD + d] = acc[bb][r];
                else atomicAdd(&outp[(b * CC + c) * DD + d], acc[bb][r]);
            }
        }
    }
}

// Atomic-fallback squash.
template<int MODE>
__global__ __launch_bounds__(512) void caps_squash(
    const float* __restrict__ sIn, float* __restrict__ vsum,
    float* __restrict__ outF)
{
    int r = blockIdx.x * blockDim.x + threadIdx.x;
    if (r >= BB * CC) return;
    const float* p = sIn + (size_t)r * DD;
    float sv[DD]; float s2 = 0.f;
    #pragma unroll
    for (int d = 0; d < DD; ++d) { sv[d] = p[d]; s2 = fmaf(sv[d], sv[d], s2); }
    float f = s2 / ((1.f + s2) * sqrtf(s2 + 1e-7f));
    #pragma unroll
    for (int d = 0; d < DD; ++d) {
        float v = f * sv[d];
        int idx = r * DD + d;
        if (MODE == 0) vsum[idx] = v;
        if (MODE == 1) vsum[idx] += v;
        if (MODE == 2) outF[idx] = v;
    }
}

extern "C" void kernel_launch(void* const* d_in, const int* in_sizes, int n_in,
                              void* d_out, int out_size, void* d_ws, size_t ws_size,
                              hipStream_t stream) {
    const float* x; const float* Wt;
    if (in_sizes[0] == BB * NN * DIN) { x = (const float*)d_in[0]; Wt = (const float*)d_in[1]; }
    else                              { Wt = (const float*)d_in[0]; x = (const float*)d_in[1]; }
    float* out = (float*)d_out;
    float* ws = (float*)d_ws;

    const size_t uhat_floats = UHATE / 2;   // bf16 elems in float-slot units
    const size_t need = UHATE * 2 + (size_t)(GA + 1) * SOUT * sizeof(float);

    if (ws_size >= need) {
        unsigned int* uhat = (unsigned int*)ws;
        float* part = ws + uhat_floats;        // [GA][SOUT]
        float* vsum = part + (size_t)GA * SOUT;
        caps_uhat_pass0<<<GA, TPB, 0, stream>>>(x, Wt, uhat, part);
        caps_reduce<0><<<BB*CC, 1024, 0, stream>>>(part, GA, vsum, nullptr);
        caps_routed<<<GB, TPB, 0, stream>>>(uhat, vsum, part);
        caps_reduce<1><<<BB*CC, 1024, 0, stream>>>(part, GB, vsum, nullptr);
        caps_routed<<<GB, TPB, 0, stream>>>(uhat, vsum, part);
        caps_reduce<2><<<BB*CC, 1024, 0, stream>>>(part, GB, vsum, out);
    } else {
        // r14-proven fallback
        const size_t wsf = ws_size / sizeof(float);
        int Gf = 0;
        const int cands[5] = {512, 256, 128, 64, 32};
        for (int ci = 0; ci < 5; ++ci)
            if (wsf >= (size_t)(cands[ci] + 1) * SOUT) { Gf = cands[ci]; break; }
        if (Gf > 0) {
            float* part = ws;
            float* vsum = ws + (size_t)Gf * SOUT;
            caps_pass<1,1><<<Gf, TPB, 0, stream>>>(x, Wt, nullptr, part);
            caps_reduce<0><<<BB*CC, 1024, 0, stream>>>(part, Gf, vsum, nullptr);
            caps_pass<0,1><<<Gf, TPB, 0, stream>>>(x, Wt, vsum, part);
            caps_reduce<1><<<BB*CC, 1024, 0, stream>>>(part, Gf, vsum, nullptr);
            caps_pass<0,1><<<Gf, TPB, 0, stream>>>(x, Wt, vsum, part);
            caps_reduce<2><<<BB*CC, 1024, 0, stream>>>(part, Gf, vsum, out);
        } else {
            float* sAcc = ws;
            float* vsum = ws + SOUT;
            hipMemsetAsync(sAcc, 0, SOUT * sizeof(float), stream);
            caps_pass<1,0><<<64, TPB, 0, stream>>>(x, Wt, nullptr, sAcc);
            caps_squash<0><<<1, 512, 0, stream>>>(sAcc, vsum, nullptr);
            hipMemsetAsync(sAcc, 0, SOUT * sizeof(float), stream);
            caps_pass<0,0><<<64, TPB, 0, stream>>>(x, Wt, vsum, sAcc);
            caps_squash<1><<<1, 512, 0, stream>>>(sAcc, vsum, nullptr);
            hipMemsetAsync(sAcc, 0, SOUT * sizeof(float), stream);
            caps_pass<0,0><<<64, TPB, 0, stream>>>(x, Wt, vsum, sAcc);
            caps_squash<2><<<1, 512, 0, stream>>>(sAcc, nullptr, out);
        }
    }
}